// Round 7
// baseline (134.709 us; speedup 1.0000x reference)
//
#include <hip/hip_runtime.h>
#include <hip/hip_bf16.h>
#include <stdint.h>

typedef unsigned short u16;
typedef unsigned int u32;
typedef unsigned long long u64;
typedef float f32x4 __attribute__((ext_vector_type(4)));
typedef short bf16x8 __attribute__((ext_vector_type(8)));
typedef u32 u32x2 __attribute__((ext_vector_type(2)));

#define MFMA(a, b, c) __builtin_amdgcn_mfma_f32_16x16x32_bf16((a), (b), (c), 0, 0, 0)

__device__ __forceinline__ void gll16(const void* g, void* lds) {
  __builtin_amdgcn_global_load_lds(
      (const __attribute__((address_space(1))) u32*)(uintptr_t)g,
      (__attribute__((address_space(3))) u32*)(uintptr_t)lds, 16, 0, 0);
}

__device__ __forceinline__ u16 f2b(float f) {
  union { __hip_bfloat16 h; u16 u; } cv;
  cv.h = __float2bfloat16(f);
  return cv.u;
}
__device__ __forceinline__ float b2f(u16 b) {
  union { u32 u; float f; } cv;
  cv.u = (u32)b << 16;
  return cv.f;
}

// swizzle: conflict-free for both transpose-writes and column-slice reads
__device__ __forceinline__ int sw(int r) { return ((r ^ (r >> 3)) & 7) << 4; }

// ---------------- fp32 -> bf16 elementwise (vectorized) ----------------
__global__ __launch_bounds__(256) void k_cvt(const float* __restrict__ in,
                                             u16* __restrict__ out, int n4) {
  int i = blockIdx.x * 256 + threadIdx.x;
  if (i >= n4) return;
  const float4 v = reinterpret_cast<const float4*>(in)[i];
  u32 lo = (u32)f2b(v.x) | ((u32)f2b(v.y) << 16);
  u32 hi = (u32)f2b(v.z) | ((u32)f2b(v.w) << 16);
  reinterpret_cast<uint2*>(out)[i] = make_uint2(lo, hi);
}

// ---------------- fp32 in[R][C] -> bf16 out[C][R] (LDS tiled transpose) ----
__global__ __launch_bounds__(256) void k_trcvt(const float* __restrict__ in,
                                               u16* __restrict__ out, int R, int C) {
  __shared__ float tile[64][65];
  const int tid = threadIdx.x;
  const int r0 = blockIdx.y * 64, c0 = blockIdx.x * 64;
  const int tr = tid >> 4;
  const int tc4 = (tid & 15) * 4;
#pragma unroll
  for (int i = 0; i < 4; ++i) {
    const float4 v = *reinterpret_cast<const float4*>(
        &in[(size_t)(r0 + i * 16 + tr) * C + c0 + tc4]);
    tile[i * 16 + tr][tc4 + 0] = v.x;
    tile[i * 16 + tr][tc4 + 1] = v.y;
    tile[i * 16 + tr][tc4 + 2] = v.z;
    tile[i * 16 + tr][tc4 + 3] = v.w;
  }
  __syncthreads();
#pragma unroll
  for (int i = 0; i < 4; ++i) {
    const int c = i * 16 + tr;
    const int r4 = tc4;
    u32 lo = (u32)f2b(tile[r4 + 0][c]) | ((u32)f2b(tile[r4 + 1][c]) << 16);
    u32 hi = (u32)f2b(tile[r4 + 2][c]) | ((u32)f2b(tile[r4 + 3][c]) << 16);
    *reinterpret_cast<uint2*>(&out[(size_t)(c0 + c) * R + r0 + r4]) =
        make_uint2(lo, hi);
  }
}

// ---------------- bf16 GEMM, m97 structure: C = A @ Bt^T ----------------
template <int F32OUT>
__global__ __launch_bounds__(256) void k_gemm(const u16* __restrict__ A,
                                              const u16* __restrict__ Bt,
                                              void* __restrict__ Cout,
                                              int M, int N, int K) {
  __shared__ u16 As[128 * 32];
  __shared__ u16 Bs[128 * 32];
  const int tid = threadIdx.x;
  const int lane = tid & 63;
  const int w = tid >> 6;
  const int wm = w >> 1, wn = w & 1;
  const int l15 = lane & 15, lg = lane >> 4;
  const int brow = blockIdx.y * 128;
  const int bcol = blockIdx.x * 128;

  f32x4 acc[4][4] = {};

  const int r0 = tid >> 2;
  const int k8 = (tid & 3) * 8;
  const u16* Ag0 = A + (size_t)(brow + r0) * K + k8;
  const u16* Ag1 = A + (size_t)(brow + 64 + r0) * K + k8;
  const u16* Bg0 = Bt + (size_t)(bcol + r0) * K + k8;
  const u16* Bg1 = Bt + (size_t)(bcol + 64 + r0) * K + k8;
  u16* Asl0 = As + tid * 8;
  u16* Asl1 = As + 2048 + tid * 8;
  u16* Bsl0 = Bs + tid * 8;
  u16* Bsl1 = Bs + 2048 + tid * 8;

  for (int k0 = 0; k0 < K; k0 += 32) {
    gll16(Ag0 + k0, Asl0);
    gll16(Ag1 + k0, Asl1);
    gll16(Bg0 + k0, Bsl0);
    gll16(Bg1 + k0, Bsl1);
    __syncthreads();
    bf16x8 a[4], b[4];
#pragma unroll
    for (int m = 0; m < 4; ++m)
      a[m] = *(const bf16x8*)&As[(wm * 64 + m * 16 + l15) * 32 + lg * 8];
#pragma unroll
    for (int n = 0; n < 4; ++n)
      b[n] = *(const bf16x8*)&Bs[(wn * 64 + n * 16 + l15) * 32 + lg * 8];
#pragma unroll
    for (int m = 0; m < 4; ++m)
#pragma unroll
      for (int n = 0; n < 4; ++n)
        acc[m][n] = MFMA(a[m], b[n], acc[m][n]);
    __syncthreads();
  }

#pragma unroll
  for (int m = 0; m < 4; ++m) {
    const int row = brow + wm * 64 + m * 16 + lg * 4;
#pragma unroll
    for (int n = 0; n < 4; ++n) {
      const int col = bcol + wn * 64 + n * 16 + l15;
#pragma unroll
      for (int r = 0; r < 4; ++r) {
        const float v = acc[m][n][r];
        if (F32OUT)
          ((float*)Cout)[(size_t)(row + r) * N + col] = v;
        else
          ((u16*)Cout)[(size_t)(row + r) * N + col] = f2b(v);
      }
    }
  }
}

// ---------------- fused causal flash attention (v7: 32 q-rows/wave) ------
// LDS-traffic analysis (r6): each wave reads the FULL K and V tile per step;
// q-rows/wave is the only lever on that amortization. v7: 128-row q-tiles,
// 32 q/wave. Pairs (k,15-k): 2(k+1)+2(16-k) = 34 uniform 64-kv steps.
// 256 blocks (1/CU), 4 waves. Max-free softmax (P=exp2(s), l via ones-MFMA),
// K staged 2 ahead (triple buf, counted vmcnt, raw s_barrier), V reg-staged
// 1 ahead -> LDS dbuf. Transposed PV (O^T), q = l15 lane-local.
__global__ __launch_bounds__(256, 2) void k_attn(const u16* __restrict__ qkv,
                                                 u16* __restrict__ y) {
  __shared__ u16 Kl[3][64 * 64];   // [t][d], sw(t)-swizzled, 24KB
  __shared__ u16 Vt[2][64 * 64];   // [d][t], sw(d)-swizzled, 16KB
  __shared__ u16 Pl[4][32 * 64];   // per-wave [q][t], sw(q), 16KB
  const int tid = threadIdx.x;
  const int lane = tid & 63;
  const int w = tid >> 6;
  const int l15 = lane & 15, lg = lane >> 4;

  // 8 XCDs x {4 heads x 8 pair-blocks}; all pair-blocks uniform (34 steps).
  const int lin = blockIdx.x;          // 0..255
  const int xcd = lin & 7;
  const int idx = lin >> 3;            // 0..31
  const int bh = xcd * 4 + (idx >> 3); // 0..31
  const int pidx = idx & 7;            // pair index 0..7
  const int b = bh >> 4, h = bh & 15;

  const u16* Qg = qkv + (size_t)(b * 2048) * 3072 + h * 64;
  const u16* Kg = Qg + 1024;
  const u16* Vg = Qg + 2048;

  const int t2 = tid >> 3;             // 0..31: owns V t-pair (2*t2, 2*t2+1)
  const int d8 = (tid & 7) * 8;        // 8 d-values per thread

  // all-ones A fragment (bf16 1.0) for the row-sum MFMA
  bf16x8 vone;
#pragma unroll
  for (int j = 0; j < 8; ++j) vone[j] = (short)0x3F80;

  // per-lane invariant LDS byte offsets (within one buffer)
  int koff[4][2], vboff[4][2], paoff[2][2], pwoff[2][4];
#pragma unroll
  for (int n = 0; n < 4; ++n) {
    const int row = n * 16 + l15;
#pragma unroll
    for (int kd = 0; kd < 2; ++kd) {
      koff[n][kd] = (row * 128 + kd * 64 + lg * 16) ^ sw(row);
      vboff[n][kd] = (row * 128 + kd * 64 + lg * 16) ^ sw(row);
    }
  }
#pragma unroll
  for (int m = 0; m < 2; ++m) {
    const int q = m * 16 + l15;
#pragma unroll
    for (int n = 0; n < 4; ++n)
      pwoff[m][n] = (q * 128 + n * 32 + lg * 8) ^ sw(q);
#pragma unroll
    for (int kg = 0; kg < 2; ++kg)
      paoff[m][kg] = (q * 128 + kg * 64 + lg * 16) ^ sw(q);
  }
  // K staging (2 gll16 per thread per tile): lane-invariant parts
  const int slotA = tid, slotB = 256 + tid;
  const int srowA = slotA >> 3, srowB = slotB >> 3;
  const int scolA = (((slotA & 7) * 16) ^ sw(srowA)) >> 1;
  const int scolB = (((slotB & 7) * 16) ^ sw(srowB)) >> 1;

  for (int pass = 0; pass < 2; ++pass) {
    const int qi = pass ? (15 - pidx) : pidx;   // q-tile (128 rows), 0..15
    const int nt = 2 * (qi + 1);                // # of 64-row KV tiles
    const int qw0 = qi * 128 + w * 32;          // wave's first q row

    // Q fragments (col q = m*16+l15, k = kd*32+lg*8), pre-scaled
    bf16x8 aq[2][2];
#pragma unroll
    for (int m = 0; m < 2; ++m)
#pragma unroll
      for (int kd = 0; kd < 2; ++kd) {
        bf16x8 v = *(const bf16x8*)&Qg[(size_t)(qw0 + m * 16 + l15) * 3072 +
                                       kd * 32 + lg * 8];
#pragma unroll
        for (int j = 0; j < 8; ++j)
          v[j] = (short)f2b(b2f((u16)v[j]) * 0.18033688011112042f);
        aq[m][kd] = v;
      }

    f32x4 acc[2][4] = {};   // O^T: col q, row d=n*16+lg*4+r
    f32x4 accl[2] = {};     // row-sums l

    // --- prologue: stage K0->Kl[0], K1->Kl[1]; V0 regs, V1 regs ---
    gll16(Kg + (size_t)srowA * 3072 + scolA, (u16*)Kl[0] + slotA * 8);
    gll16(Kg + (size_t)srowB * 3072 + scolB, (u16*)Kl[0] + slotB * 8);
    bf16x8 v00 = *(const bf16x8*)&Vg[(size_t)(2 * t2) * 3072 + d8];
    bf16x8 v01 = *(const bf16x8*)&Vg[(size_t)(2 * t2 + 1) * 3072 + d8];
    gll16(Kg + (size_t)(64 + srowA) * 3072 + scolA, (u16*)Kl[1] + slotA * 8);
    gll16(Kg + (size_t)(64 + srowB) * 3072 + scolB, (u16*)Kl[1] + slotB * 8);
    bf16x8 va0 = *(const bf16x8*)&Vg[(size_t)(64 + 2 * t2) * 3072 + d8];
    bf16x8 va1 = *(const bf16x8*)&Vg[(size_t)(64 + 2 * t2 + 1) * 3072 + d8];

    // write V0 -> Vt[0]
#pragma unroll
    for (int j = 0; j < 8; ++j) {
      const int d = d8 + j;
      const u32 val = (u32)(u16)v00[j] | ((u32)(u16)v01[j] << 16);
      *(u32*)((char*)Vt[0] + ((d * 128 + t2 * 4) ^ sw(d))) = val;
    }
    // K0 must be in LDS; K1/V1 (4 ops) stay in flight
    asm volatile("s_waitcnt vmcnt(4) lgkmcnt(0)" ::: "memory");
    __builtin_amdgcn_s_barrier();
    __builtin_amdgcn_sched_barrier(0);

    const char* kR = (const char*)Kl[0];
    const char* kN = (const char*)Kl[1];
    char* kN2 = (char*)Kl[2];
    const char* vR = (const char*)Vt[0];
    char* vW = (char*)Vt[1];

    for (int t = 0; t < nt; ++t) {
      // ---- issue stage for tile t+2 (clamped; always 4 VMEM ops) ----
      const int tf = (t + 2 < 31 ? t + 2 : 31);
      const size_t tfo = (size_t)(tf * 64) * 3072;
      gll16(Kg + tfo + (size_t)srowA * 3072 + scolA, (u16*)kN2 + slotA * 8);
      gll16(Kg + tfo + (size_t)srowB * 3072 + scolB, (u16*)kN2 + slotB * 8);
      const bf16x8 vf0 = *(const bf16x8*)&Vg[tfo + (size_t)(2 * t2) * 3072 + d8];
      const bf16x8 vf1 = *(const bf16x8*)&Vg[tfo + (size_t)(2 * t2 + 1) * 3072 + d8];

      // ---- S^T = K Q^T : lane holds t-row = n*16+lg*4+r, q = m*16+l15 ----
      f32x4 st[2][4];
#pragma unroll
      for (int n = 0; n < 4; ++n) {
        const bf16x8 bk0 = *(const bf16x8*)(kR + koff[n][0]);
        const bf16x8 bk1 = *(const bf16x8*)(kR + koff[n][1]);
#pragma unroll
        for (int m = 0; m < 2; ++m) {
          f32x4 z = {};
          z = MFMA(bk0, aq[m][0], z);
          z = MFMA(bk1, aq[m][1], z);
          st[m][n] = z;
        }
      }

      // ---- max-free softmax numerator: P = exp2(s) (mask last 2 tiles) ----
      if (t >= nt - 2) {
        const int t0 = t * 64;
#pragma unroll
        for (int m = 0; m < 2; ++m) {
          const int qrow = qw0 + m * 16 + l15;
#pragma unroll
          for (int n = 0; n < 4; ++n)
#pragma unroll
            for (int r = 0; r < 4; ++r) {
              const int kkg = t0 + n * 16 + lg * 4 + r;
              st[m][n][r] = (kkg > qrow) ? -1e30f : st[m][n][r];
            }
        }
      }
#pragma unroll
      for (int m = 0; m < 2; ++m)
#pragma unroll
        for (int n = 0; n < 4; ++n)
#pragma unroll
          for (int r = 0; r < 4; ++r) st[m][n][r] = exp2f(st[m][n][r]);

      // ---- write P[q][t] as u32x2 (conflict-free b64) ----
#pragma unroll
      for (int m = 0; m < 2; ++m)
#pragma unroll
        for (int n = 0; n < 4; ++n) {
          u32x2 pk;
          pk[0] = (u32)f2b(st[m][n][0]) | ((u32)f2b(st[m][n][1]) << 16);
          pk[1] = (u32)f2b(st[m][n][2]) | ((u32)f2b(st[m][n][3]) << 16);
          *(u32x2*)((char*)Pl[w] + pwoff[m][n]) = pk;
        }

      // ---- O^T += V^T P ; l += 1^T P (ones-row MFMA) ----
      bf16x8 pa[2][2];
#pragma unroll
      for (int m = 0; m < 2; ++m)
#pragma unroll
        for (int kg = 0; kg < 2; ++kg)
          pa[m][kg] = *(const bf16x8*)((const char*)Pl[w] + paoff[m][kg]);
#pragma unroll
      for (int m = 0; m < 2; ++m) {
        accl[m] = MFMA(vone, pa[m][0], accl[m]);
        accl[m] = MFMA(vone, pa[m][1], accl[m]);
      }
#pragma unroll
      for (int n = 0; n < 4; ++n) {
        const bf16x8 vb0 = *(const bf16x8*)(vR + vboff[n][0]);
        const bf16x8 vb1 = *(const bf16x8*)(vR + vboff[n][1]);
#pragma unroll
        for (int m = 0; m < 2; ++m) {
          acc[m][n] = MFMA(vb0, pa[m][0], acc[m][n]);
          acc[m][n] = MFMA(vb1, pa[m][1], acc[m][n]);
        }
      }

      // ---- publish V(t+1) regs -> LDS (write-late, T14) ----
      if (t < nt - 1) {
#pragma unroll
        for (int j = 0; j < 8; ++j) {
          const int d = d8 + j;
          const u32 val = (u32)(u16)va0[j] | ((u32)(u16)va1[j] << 16);
          *(u32*)(vW + ((d * 128 + t2 * 4) ^ sw(d))) = val;
        }
      }
      va0 = vf0; va1 = vf1;
      // rotate K triple-buffer, swap V dbuf
      const char* kt = kR; kR = kN; kN = kN2; kN2 = (char*)kt;
      char* vt_ = (char*)vR; vR = vW; vW = vt_;

      // counted-vmcnt barrier: exactly the 4 tile-(t+2) VMEM ops in flight
      asm volatile("s_waitcnt vmcnt(4) lgkmcnt(0)" ::: "memory");
      __builtin_amdgcn_s_barrier();
      __builtin_amdgcn_sched_barrier(0);
    }

    // ---- epilogue: normalize (lane-local, l = accl[m][0]) and store y ----
#pragma unroll
    for (int m = 0; m < 2; ++m) {
      const float linv = 1.0f / accl[m][0];
      const size_t yrow = (size_t)(b * 2048 + qw0 + m * 16 + l15) * 1024 + h * 64;
#pragma unroll
      for (int n = 0; n < 4; ++n) {
        const u64 pk = (u64)f2b(acc[m][n][0] * linv) |
                       ((u64)f2b(acc[m][n][1] * linv) << 16) |
                       ((u64)f2b(acc[m][n][2] * linv) << 32) |
                       ((u64)f2b(acc[m][n][3] * linv) << 48);
        *(u64*)&y[yrow + n * 16 + lg * 4] = pk;
      }
    }

    // pass boundary: full drain (junk prefetches must land before reuse)
    asm volatile("s_waitcnt vmcnt(0) lgkmcnt(0)" ::: "memory");
    __builtin_amdgcn_s_barrier();
    __builtin_amdgcn_sched_barrier(0);
  }
}

// ---------------- host launch ----------------
extern "C" void kernel_launch(void* const* d_in, const int* in_sizes, int n_in,
                              void* d_out, int out_size, void* d_ws, size_t ws_size,
                              hipStream_t stream) {
  const float* x  = (const float*)d_in[0];   // [2,2048,1024]
  const float* wa = (const float*)d_in[1];   // [1024,3072]
  const float* wp = (const float*)d_in[2];   // [1024,1024]
  float* out = (float*)d_out;                // [2,2048,1024] fp32

  u16* xb  = (u16*)d_ws;                 // [4096][1024] bf16
  u16* wat = xb + (size_t)4096 * 1024;   // [3072][1024] bf16 (w_attn^T)
  u16* wpt = wat + (size_t)3072 * 1024;  // [1024][1024] bf16 (w_proj^T)
  u16* qkv = wpt + (size_t)1024 * 1024;  // [4096][3072] bf16
  u16* yb  = qkv + (size_t)4096 * 3072;  // [4096][1024] bf16

  k_cvt<<<4096, 256, 0, stream>>>(x, xb, 4096 * 1024 / 4);
  k_trcvt<<<dim3(3072 / 64, 1024 / 64), 256, 0, stream>>>(wa, wat, 1024, 3072);
  k_trcvt<<<dim3(1024 / 64, 1024 / 64), 256, 0, stream>>>(wp, wpt, 1024, 1024);

  // qkv = x @ w_attn   (bf16 out)
  k_gemm<0><<<dim3(3072 / 128, 4096 / 128), 256, 0, stream>>>(xb, wat, qkv, 4096, 3072, 1024);

  // fused causal attention -> y [4096][1024] bf16
  k_attn<<<256, 256, 0, stream>>>(qkv, yb);

  // out = y @ w_proj   (fp32 out)
  k_gemm<1><<<dim3(1024 / 128, 4096 / 128), 256, 0, stream>>>(yb, wpt, out, 4096, 1024, 1024);
}

// Round 9
// 125.452 us; speedup vs baseline: 1.0738x; 1.0738x over previous
//
#include <hip/hip_runtime.h>
#include <hip/hip_bf16.h>
#include <stdint.h>

typedef unsigned short u16;
typedef unsigned int u32;
typedef unsigned long long u64;
typedef float f32x4 __attribute__((ext_vector_type(4)));
typedef float f32x16 __attribute__((ext_vector_type(16)));
typedef short bf16x8 __attribute__((ext_vector_type(8)));
typedef u32 u32x4 __attribute__((ext_vector_type(4)));

#define MFMA(a, b, c) __builtin_amdgcn_mfma_f32_16x16x32_bf16((a), (b), (c), 0, 0, 0)
#define MFMA32(a, b, c) __builtin_amdgcn_mfma_f32_32x32x16_bf16((a), (b), (c), 0, 0, 0)

__device__ __forceinline__ void gll16(const void* g, void* lds) {
  __builtin_amdgcn_global_load_lds(
      (const __attribute__((address_space(1))) u32*)(uintptr_t)g,
      (__attribute__((address_space(3))) u32*)(uintptr_t)lds, 16, 0, 0);
}

__device__ __forceinline__ u16 f2b(float f) {
  union { __hip_bfloat16 h; u16 u; } cv;
  cv.h = __float2bfloat16(f);
  return cv.u;
}
__device__ __forceinline__ float b2f(u16 b) {
  union { u32 u; float f; } cv;
  cv.u = (u32)b << 16;
  return cv.f;
}
__device__ __forceinline__ u32 cvtpk(float lo, float hi) {
  u32 r;
  asm("v_cvt_pk_bf16_f32 %0, %1, %2" : "=v"(r) : "v"(lo), "v"(hi));
  return r;
}

// swizzle: conflict-free for both transpose-writes and column-slice reads
__device__ __forceinline__ int sw(int r) { return ((r ^ (r >> 3)) & 7) << 4; }

// ---------------- fp32 -> bf16 elementwise (vectorized) ----------------
__global__ __launch_bounds__(256) void k_cvt(const float* __restrict__ in,
                                             u16* __restrict__ out, int n4) {
  int i = blockIdx.x * 256 + threadIdx.x;
  if (i >= n4) return;
  const float4 v = reinterpret_cast<const float4*>(in)[i];
  u32 lo = (u32)f2b(v.x) | ((u32)f2b(v.y) << 16);
  u32 hi = (u32)f2b(v.z) | ((u32)f2b(v.w) << 16);
  reinterpret_cast<uint2*>(out)[i] = make_uint2(lo, hi);
}

// ---------------- fp32 in[R][C] -> bf16 out[C][R] (LDS tiled transpose) ----
__global__ __launch_bounds__(256) void k_trcvt(const float* __restrict__ in,
                                               u16* __restrict__ out, int R, int C) {
  __shared__ float tile[64][65];
  const int tid = threadIdx.x;
  const int r0 = blockIdx.y * 64, c0 = blockIdx.x * 64;
  const int tr = tid >> 4;
  const int tc4 = (tid & 15) * 4;
#pragma unroll
  for (int i = 0; i < 4; ++i) {
    const float4 v = *reinterpret_cast<const float4*>(
        &in[(size_t)(r0 + i * 16 + tr) * C + c0 + tc4]);
    tile[i * 16 + tr][tc4 + 0] = v.x;
    tile[i * 16 + tr][tc4 + 1] = v.y;
    tile[i * 16 + tr][tc4 + 2] = v.z;
    tile[i * 16 + tr][tc4 + 3] = v.w;
  }
  __syncthreads();
#pragma unroll
  for (int i = 0; i < 4; ++i) {
    const int c = i * 16 + tr;
    const int r4 = tc4;
    u32 lo = (u32)f2b(tile[r4 + 0][c]) | ((u32)f2b(tile[r4 + 1][c]) << 16);
    u32 hi = (u32)f2b(tile[r4 + 2][c]) | ((u32)f2b(tile[r4 + 3][c]) << 16);
    *reinterpret_cast<uint2*>(&out[(size_t)(c0 + c) * R + r0 + r4]) =
        make_uint2(lo, hi);
  }
}

// ---------------- bf16 GEMM, m97 structure: C = A @ Bt^T ----------------
template <int F32OUT>
__global__ __launch_bounds__(256) void k_gemm(const u16* __restrict__ A,
                                              const u16* __restrict__ Bt,
                                              void* __restrict__ Cout,
                                              int M, int N, int K) {
  __shared__ u16 As[128 * 32];
  __shared__ u16 Bs[128 * 32];
  const int tid = threadIdx.x;
  const int lane = tid & 63;
  const int w = tid >> 6;
  const int wm = w >> 1, wn = w & 1;
  const int l15 = lane & 15, lg = lane >> 4;
  const int brow = blockIdx.y * 128;
  const int bcol = blockIdx.x * 128;

  f32x4 acc[4][4] = {};

  const int r0 = tid >> 2;
  const int k8 = (tid & 3) * 8;
  const u16* Ag0 = A + (size_t)(brow + r0) * K + k8;
  const u16* Ag1 = A + (size_t)(brow + 64 + r0) * K + k8;
  const u16* Bg0 = Bt + (size_t)(bcol + r0) * K + k8;
  const u16* Bg1 = Bt + (size_t)(bcol + 64 + r0) * K + k8;
  u16* Asl0 = As + tid * 8;
  u16* Asl1 = As + 2048 + tid * 8;
  u16* Bsl0 = Bs + tid * 8;
  u16* Bsl1 = Bs + 2048 + tid * 8;

  for (int k0 = 0; k0 < K; k0 += 32) {
    gll16(Ag0 + k0, Asl0);
    gll16(Ag1 + k0, Asl1);
    gll16(Bg0 + k0, Bsl0);
    gll16(Bg1 + k0, Bsl1);
    __syncthreads();
    bf16x8 a[4], b[4];
#pragma unroll
    for (int m = 0; m < 4; ++m)
      a[m] = *(const bf16x8*)&As[(wm * 64 + m * 16 + l15) * 32 + lg * 8];
#pragma unroll
    for (int n = 0; n < 4; ++n)
      b[n] = *(const bf16x8*)&Bs[(wn * 64 + n * 16 + l15) * 32 + lg * 8];
#pragma unroll
    for (int m = 0; m < 4; ++m)
#pragma unroll
      for (int n = 0; n < 4; ++n)
        acc[m][n] = MFMA(a[m], b[n], acc[m][n]);
    __syncthreads();
  }

#pragma unroll
  for (int m = 0; m < 4; ++m) {
    const int row = brow + wm * 64 + m * 16 + lg * 4;
#pragma unroll
    for (int n = 0; n < 4; ++n) {
      const int col = bcol + wn * 64 + n * 16 + l15;
#pragma unroll
      for (int r = 0; r < 4; ++r) {
        const float v = acc[m][n][r];
        if (F32OUT)
          ((float*)Cout)[(size_t)(row + r) * N + col] = v;
        else
          ((u16*)Cout)[(size_t)(row + r) * N + col] = f2b(v);
      }
    }
  }
}

// ---------------- fused causal flash attention (v9) ----------------------
// v8 structure with the half-wave exchange done via __shfl_xor(.,32) +
// select (known semantics) instead of v_permlane32_swap (whose tied-operand
// asm semantics produced a t-permutation of P in r8 -> absmax 5.6).
// 256 blocks x 512 thr (8 waves = 4 q-subs x 2 t-subs). 128-q tiles paired
// (k,15-k) -> 34 uniform 64-kv steps, 1 block/CU, 2 waves/SIMD.
// 32x32x16 MFMA; swapped QK^T -> S^T lane-local per q; P stays IN REGISTER.
// Max-free softmax (P=exp2(s), l via ones-MFMA). K staged 2-ahead
// (tri-buffer gll), V reg-staged 1-ahead. Single barrier per step with
// counted vmcnt(1). Per-pass cross-t-sub O/l merge via padded LDS.
__global__ __launch_bounds__(512, 1) void k_attn(const u16* __restrict__ qkv,
                                                 u16* __restrict__ y) {
  __shared__ u16 Kl[3][64 * 64];     // [t][d] sw(t)      24KB
  __shared__ u16 Vt[2][64 * 64];     // [d][t] sw(d)      16KB
  __shared__ float Om[4][64][33];    // O merge (padded)  33.8KB
  __shared__ float Lm[4][2][32];     // l partials        1KB
  const int tid = threadIdx.x;
  const int lane = tid & 63;
  const int w = tid >> 6;
  const int qsub = w & 3, tsub = w >> 2;
  const int l31 = lane & 31, hi = lane >> 5;

  const int lin = blockIdx.x;          // 0..255
  const int xcd = lin & 7;
  const int idx = lin >> 3;            // 0..31
  const int bh = xcd * 4 + (idx >> 3); // 0..31
  const int pidx = idx & 7;            // pair index 0..7
  const int b = bh >> 4, h = bh & 15;

  const u16* Qg = qkv + (size_t)(b * 2048) * 3072 + h * 64;
  const u16* Kg = Qg + 1024;
  const u16* Vg = Qg + 2048;

  // K staging: 512 thr x 16B = 8KB tile, pre-swizzled source
  const int srow = tid >> 3;                             // 0..63
  const int scol = (((tid & 7) * 16) ^ sw(srow)) >> 1;   // u16 units
  // V staging (tid<256, waves 0-3): t-pair + 8 d values (v6 scheme)
  const bool vstage = (tid < 256);
  const int t2 = (tid & 255) >> 3;
  const int d8 = (tid & 7) * 8;

  bf16x8 vone;
#pragma unroll
  for (int j = 0; j < 8; ++j) vone[j] = (short)0x3F80;

  // LDS read offsets (lane-invariant)
  const int trow = tsub * 32 + l31;
  int koff[4];
#pragma unroll
  for (int ks = 0; ks < 4; ++ks)
    koff[ks] = trow * 128 + (((ks * 16 + hi * 8) * 2) ^ sw(trow));
  int voff[2][2];
#pragma unroll
  for (int db = 0; db < 2; ++db) {
    const int dl = db * 32 + l31;
#pragma unroll
    for (int ks = 0; ks < 2; ++ks)
      voff[db][ks] = dl * 128 + (((tsub * 32 + ks * 16 + hi * 8) * 2) ^ sw(dl));
  }

  for (int pass = 0; pass < 2; ++pass) {
    const int qi = pass ? (15 - pidx) : pidx;   // q-tile (128 rows), 0..15
    const int nt = 2 * (qi + 1);                // # of 64-row KV tiles
    const int qb = qi * 128;
    const int qrow = qb + qsub * 32 + l31;      // this lane's q row

    // Q B-frags (col q = l31, k = ks*16 + hi*8 + j), pre-scaled
    bf16x8 aq[4];
#pragma unroll
    for (int ks = 0; ks < 4; ++ks) {
      bf16x8 v = *(const bf16x8*)&Qg[(size_t)qrow * 3072 + ks * 16 + hi * 8];
#pragma unroll
      for (int j = 0; j < 8; ++j)
        v[j] = (short)f2b(b2f((u16)v[j]) * 0.18033688011112042f);
      aq[ks] = v;
    }

    f32x16 acc0 = {}, acc1 = {}, accl = {};  // O^T d-blocks 0/1, l

    // --- prologue: V0,V1 loads first; K0,K1 gll after (K newest in queue) ---
    bf16x8 va0, va1;
    {
      bf16x8 v00, v01;
      if (vstage) {
        v00 = *(const bf16x8*)&Vg[(size_t)(2 * t2) * 3072 + d8];
        v01 = *(const bf16x8*)&Vg[(size_t)(2 * t2 + 1) * 3072 + d8];
        va0 = *(const bf16x8*)&Vg[(size_t)(64 + 2 * t2) * 3072 + d8];
        va1 = *(const bf16x8*)&Vg[(size_t)(64 + 2 * t2 + 1) * 3072 + d8];
      }
      gll16(Kg + (size_t)srow * 3072 + scol, (u16*)Kl[0] + tid * 8);
      gll16(Kg + (size_t)(64 + srow) * 3072 + scol, (u16*)Kl[1] + tid * 8);
      if (vstage) {
#pragma unroll
        for (int j = 0; j < 8; ++j) {
          const int d = d8 + j;
          const u32 val = (u32)(u16)v00[j] | ((u32)(u16)v01[j] << 16);
          *(u32*)((char*)Vt[0] + ((d * 128 + t2 * 4) ^ sw(d))) = val;
        }
      }
    }
    asm volatile("s_waitcnt vmcnt(1) lgkmcnt(0)" ::: "memory");
    __builtin_amdgcn_s_barrier();
    __builtin_amdgcn_sched_barrier(0);

    const char* kR = (const char*)Kl[0];
    const char* kN = (const char*)Kl[1];
    char* kN2 = (char*)Kl[2];
    const char* vR = (const char*)Vt[0];
    char* vW = (char*)Vt[1];

    for (int t = 0; t < nt; ++t) {
      // ---- issue V(t+2) loads then K(t+2) gll (clamped) ----
      const int tf = (t + 2 < 31 ? t + 2 : 31);
      bf16x8 vf0, vf1;
      if (vstage) {
        vf0 = *(const bf16x8*)&Vg[(size_t)(tf * 64 + 2 * t2) * 3072 + d8];
        vf1 = *(const bf16x8*)&Vg[(size_t)(tf * 64 + 2 * t2 + 1) * 3072 + d8];
      }
      gll16(Kg + (size_t)(tf * 64 + srow) * 3072 + scol, (u16*)kN2 + tid * 8);

      // ---- S^T = K Q^T (32x32): lane col q = l31, rows t_local 0..31 ----
      f32x16 s = {};
#pragma unroll
      for (int ks = 0; ks < 4; ++ks) {
        const bf16x8 kf = *(const bf16x8*)(kR + koff[ks]);
        s = MFMA32(kf, aq[ks], s);
      }

      // ---- max-free softmax numerator (mask last 2 tiles) ----
      float p[16];
      if (t >= nt - 2) {
#pragma unroll
        for (int r = 0; r < 16; ++r) {
          const int kkg = t * 64 + tsub * 32 + (r & 3) + 8 * (r >> 2) + 4 * hi;
          p[r] = exp2f(kkg > qrow ? -1e30f : s[r]);
        }
      } else {
#pragma unroll
        for (int r = 0; r < 16; ++r) p[r] = exp2f(s[r]);
      }

      // ---- in-register P -> PV B-frags: cvt_pk + shfl_xor(32) exchange ----
      // reg r holds t_local = (r&3) + 8*(r>>2) + 4*hi; B-frag word wi at
      // lane (q,hi) must hold t = 8*hi + 2*wi (+1) [pb0], 16 + ... [pb1].
      const u32 X0 = cvtpk(p[0], p[1]),   X1 = cvtpk(p[2], p[3]);
      const u32 X2 = cvtpk(p[4], p[5]),   X3 = cvtpk(p[6], p[7]);
      const u32 X4 = cvtpk(p[8], p[9]),   X5 = cvtpk(p[10], p[11]);
      const u32 X6 = cvtpk(p[12], p[13]), X7 = cvtpk(p[14], p[15]);
      const u32 sx0 = (u32)__shfl_xor((int)X0, 32);
      const u32 sx1 = (u32)__shfl_xor((int)X1, 32);
      const u32 sx2 = (u32)__shfl_xor((int)X2, 32);
      const u32 sx3 = (u32)__shfl_xor((int)X3, 32);
      const u32 sx4 = (u32)__shfl_xor((int)X4, 32);
      const u32 sx5 = (u32)__shfl_xor((int)X5, 32);
      const u32 sx6 = (u32)__shfl_xor((int)X6, 32);
      const u32 sx7 = (u32)__shfl_xor((int)X7, 32);
      union { u32x4 u; bf16x8 h; } c0, c1;
      c0.u[0] = hi ? sx2 : X0;   // t(0,1)@hi0  / t(8,9)@hi1
      c0.u[1] = hi ? sx3 : X1;   // t(2,3)      / t(10,11)
      c0.u[2] = hi ? X2 : sx0;   // t(4,5)      / t(12,13)
      c0.u[3] = hi ? X3 : sx1;   // t(6,7)      / t(14,15)
      c1.u[0] = hi ? sx6 : X4;   // t(16,17)    / t(24,25)
      c1.u[1] = hi ? sx7 : X5;   // t(18,19)    / t(26,27)
      c1.u[2] = hi ? X6 : sx4;   // t(20,21)    / t(28,29)
      c1.u[3] = hi ? X7 : sx5;   // t(22,23)    / t(30,31)
      const bf16x8 pb0 = c0.h, pb1 = c1.h;

      // ---- l += 1^T P ; O^T += V^T P ----
      accl = MFMA32(vone, pb0, accl);
      accl = MFMA32(vone, pb1, accl);
      const bf16x8 vb00 = *(const bf16x8*)(vR + voff[0][0]);
      const bf16x8 vb01 = *(const bf16x8*)(vR + voff[0][1]);
      const bf16x8 vb10 = *(const bf16x8*)(vR + voff[1][0]);
      const bf16x8 vb11 = *(const bf16x8*)(vR + voff[1][1]);
      acc0 = MFMA32(vb00, pb0, acc0);
      acc0 = MFMA32(vb01, pb1, acc0);
      acc1 = MFMA32(vb10, pb0, acc1);
      acc1 = MFMA32(vb11, pb1, acc1);

      // ---- publish V(t+1) regs -> LDS (write-late, T14) ----
      if (vstage && t < nt - 1) {
#pragma unroll
        for (int j = 0; j < 8; ++j) {
          const int d = d8 + j;
          const u32 val = (u32)(u16)va0[j] | ((u32)(u16)va1[j] << 16);
          *(u32*)(vW + ((d * 128 + t2 * 4) ^ sw(d))) = val;
        }
      }
      va0 = vf0; va1 = vf1;
      const char* kt = kR; kR = kN; kN = kN2; kN2 = (char*)kt;
      char* vt_ = (char*)vR; vR = vW; vW = vt_;

      // counted barrier: K(t+2) stays in flight, K(t+1)/V drained
      asm volatile("s_waitcnt vmcnt(1) lgkmcnt(0)" ::: "memory");
      __builtin_amdgcn_s_barrier();
      __builtin_amdgcn_sched_barrier(0);
    }

    // ---- pass epilogue: drain, cross-t-sub merge, normalize, store ----
    asm volatile("s_waitcnt vmcnt(0) lgkmcnt(0)" ::: "memory");
    __builtin_amdgcn_s_barrier();
    __builtin_amdgcn_sched_barrier(0);

    if (tsub == 1) {
#pragma unroll
      for (int r = 0; r < 16; ++r) {
        const int d = (r & 3) + 8 * (r >> 2) + 4 * hi;
        Om[qsub][d][l31] = acc0[r];
        Om[qsub][32 + d][l31] = acc1[r];
      }
      Lm[qsub][1][l31] = accl[0];
    } else {
      Lm[qsub][0][l31] = accl[0];
    }
    __syncthreads();
    if (tsub == 0) {
      const float linv = 1.0f / (Lm[qsub][0][l31] + Lm[qsub][1][l31]);
#pragma unroll
      for (int r = 0; r < 16; ++r) {
        const int d = (r & 3) + 8 * (r >> 2) + 4 * hi;
        Om[qsub][d][l31] = (acc0[r] + Om[qsub][d][l31]) * linv;
        Om[qsub][32 + d][l31] = (acc1[r] + Om[qsub][32 + d][l31]) * linv;
      }
    }
    __syncthreads();
    {
      // coalesced y store: thread -> (q row, 16-d group)
      const int qloc = tid >> 2;
      const int dgr = (tid & 3) * 16;
      const size_t yo = (size_t)(b * 2048 + qb + qloc) * 1024 + h * 64 + dgr;
      u32 o[8];
#pragma unroll
      for (int jj = 0; jj < 8; ++jj)
        o[jj] = cvtpk(Om[qloc >> 5][dgr + 2 * jj][qloc & 31],
                      Om[qloc >> 5][dgr + 2 * jj + 1][qloc & 31]);
      u32x4 s0 = {o[0], o[1], o[2], o[3]};
      u32x4 s1 = {o[4], o[5], o[6], o[7]};
      *(u32x4*)&y[yo] = s0;
      *(u32x4*)&y[yo + 8] = s1;
    }
    __syncthreads();
  }
}

// ---------------- host launch ----------------
extern "C" void kernel_launch(void* const* d_in, const int* in_sizes, int n_in,
                              void* d_out, int out_size, void* d_ws, size_t ws_size,
                              hipStream_t stream) {
  const float* x  = (const float*)d_in[0];   // [2,2048,1024]
  const float* wa = (const float*)d_in[1];   // [1024,3072]
  const float* wp = (const float*)d_in[2];   // [1024,1024]
  float* out = (float*)d_out;                // [2,2048,1024] fp32

  u16* xb  = (u16*)d_ws;                 // [4096][1024] bf16
  u16* wat = xb + (size_t)4096 * 1024;   // [3072][1024] bf16 (w_attn^T)
  u16* wpt = wat + (size_t)3072 * 1024;  // [1024][1024] bf16 (w_proj^T)
  u16* qkv = wpt + (size_t)1024 * 1024;  // [4096][3072] bf16
  u16* yb  = qkv + (size_t)4096 * 3072;  // [4096][1024] bf16

  k_cvt<<<4096, 256, 0, stream>>>(x, xb, 4096 * 1024 / 4);
  k_trcvt<<<dim3(3072 / 64, 1024 / 64), 256, 0, stream>>>(wa, wat, 1024, 3072);
  k_trcvt<<<dim3(1024 / 64, 1024 / 64), 256, 0, stream>>>(wp, wpt, 1024, 1024);

  // qkv = x @ w_attn   (bf16 out)
  k_gemm<0><<<dim3(3072 / 128, 4096 / 128), 256, 0, stream>>>(xb, wat, qkv, 4096, 3072, 1024);

  // fused causal attention -> y [4096][1024] bf16
  k_attn<<<256, 512, 0, stream>>>(qkv, yb);

  // out = y @ w_proj   (fp32 out)
  k_gemm<1><<<dim3(1024 / 128, 4096 / 128), 256, 0, stream>>>(yb, wpt, out, 4096, 1024, 1024);
}

// Round 10
// 119.030 us; speedup vs baseline: 1.1317x; 1.0540x over previous
//
#include <hip/hip_runtime.h>
#include <hip/hip_bf16.h>
#include <stdint.h>

typedef unsigned short u16;
typedef unsigned int u32;
typedef unsigned long long u64;
typedef float f32x4 __attribute__((ext_vector_type(4)));
typedef float f32x16 __attribute__((ext_vector_type(16)));
typedef short bf16x8 __attribute__((ext_vector_type(8)));
typedef u32 u32x4 __attribute__((ext_vector_type(4)));

#define MFMA(a, b, c) __builtin_amdgcn_mfma_f32_16x16x32_bf16((a), (b), (c), 0, 0, 0)
#define MFMA32(a, b, c) __builtin_amdgcn_mfma_f32_32x32x16_bf16((a), (b), (c), 0, 0, 0)

__device__ __forceinline__ void gll16(const void* g, void* lds) {
  __builtin_amdgcn_global_load_lds(
      (const __attribute__((address_space(1))) u32*)(uintptr_t)g,
      (__attribute__((address_space(3))) u32*)(uintptr_t)lds, 16, 0, 0);
}

__device__ __forceinline__ u16 f2b(float f) {
  union { __hip_bfloat16 h; u16 u; } cv;
  cv.h = __float2bfloat16(f);
  return cv.u;
}
__device__ __forceinline__ float b2f(u16 b) {
  union { u32 u; float f; } cv;
  cv.u = (u32)b << 16;
  return cv.f;
}
__device__ __forceinline__ u32 cvtpk(float lo, float hi) {
  u32 r;
  asm("v_cvt_pk_bf16_f32 %0, %1, %2" : "=v"(r) : "v"(lo), "v"(hi));
  return r;
}

// swizzle: conflict-free for both transpose-writes and column-slice reads
__device__ __forceinline__ int sw(int r) { return ((r ^ (r >> 3)) & 7) << 4; }

// ---------------- fp32 -> bf16 elementwise (vectorized) ----------------
__global__ __launch_bounds__(256) void k_cvt(const float* __restrict__ in,
                                             u16* __restrict__ out, int n4) {
  int i = blockIdx.x * 256 + threadIdx.x;
  if (i >= n4) return;
  const float4 v = reinterpret_cast<const float4*>(in)[i];
  u32 lo = (u32)f2b(v.x) | ((u32)f2b(v.y) << 16);
  u32 hi = (u32)f2b(v.z) | ((u32)f2b(v.w) << 16);
  reinterpret_cast<uint2*>(out)[i] = make_uint2(lo, hi);
}

// ---------------- fp32 in[R][C] -> bf16 out[C][R] (LDS tiled transpose) ----
__global__ __launch_bounds__(256) void k_trcvt(const float* __restrict__ in,
                                               u16* __restrict__ out, int R, int C) {
  __shared__ float tile[64][65];
  const int tid = threadIdx.x;
  const int r0 = blockIdx.y * 64, c0 = blockIdx.x * 64;
  const int tr = tid >> 4;
  const int tc4 = (tid & 15) * 4;
#pragma unroll
  for (int i = 0; i < 4; ++i) {
    const float4 v = *reinterpret_cast<const float4*>(
        &in[(size_t)(r0 + i * 16 + tr) * C + c0 + tc4]);
    tile[i * 16 + tr][tc4 + 0] = v.x;
    tile[i * 16 + tr][tc4 + 1] = v.y;
    tile[i * 16 + tr][tc4 + 2] = v.z;
    tile[i * 16 + tr][tc4 + 3] = v.w;
  }
  __syncthreads();
#pragma unroll
  for (int i = 0; i < 4; ++i) {
    const int c = i * 16 + tr;
    const int r4 = tc4;
    u32 lo = (u32)f2b(tile[r4 + 0][c]) | ((u32)f2b(tile[r4 + 1][c]) << 16);
    u32 hi = (u32)f2b(tile[r4 + 2][c]) | ((u32)f2b(tile[r4 + 3][c]) << 16);
    *reinterpret_cast<uint2*>(&out[(size_t)(c0 + c) * R + r0 + r4]) =
        make_uint2(lo, hi);
  }
}

// ---------------- bf16 GEMM, m97 structure: C = A @ Bt^T (GEMM2) ---------
template <int F32OUT>
__global__ __launch_bounds__(256) void k_gemm(const u16* __restrict__ A,
                                              const u16* __restrict__ Bt,
                                              void* __restrict__ Cout,
                                              int M, int N, int K) {
  __shared__ u16 As[128 * 32];
  __shared__ u16 Bs[128 * 32];
  const int tid = threadIdx.x;
  const int lane = tid & 63;
  const int w = tid >> 6;
  const int wm = w >> 1, wn = w & 1;
  const int l15 = lane & 15, lg = lane >> 4;
  const int brow = blockIdx.y * 128;
  const int bcol = blockIdx.x * 128;

  f32x4 acc[4][4] = {};

  const int r0 = tid >> 2;
  const int k8 = (tid & 3) * 8;
  const u16* Ag0 = A + (size_t)(brow + r0) * K + k8;
  const u16* Ag1 = A + (size_t)(brow + 64 + r0) * K + k8;
  const u16* Bg0 = Bt + (size_t)(bcol + r0) * K + k8;
  const u16* Bg1 = Bt + (size_t)(bcol + 64 + r0) * K + k8;
  u16* Asl0 = As + tid * 8;
  u16* Asl1 = As + 2048 + tid * 8;
  u16* Bsl0 = Bs + tid * 8;
  u16* Bsl1 = Bs + 2048 + tid * 8;

  for (int k0 = 0; k0 < K; k0 += 32) {
    gll16(Ag0 + k0, Asl0);
    gll16(Ag1 + k0, Asl1);
    gll16(Bg0 + k0, Bsl0);
    gll16(Bg1 + k0, Bsl1);
    __syncthreads();
    bf16x8 a[4], b[4];
#pragma unroll
    for (int m = 0; m < 4; ++m)
      a[m] = *(const bf16x8*)&As[(wm * 64 + m * 16 + l15) * 32 + lg * 8];
#pragma unroll
    for (int n = 0; n < 4; ++n)
      b[n] = *(const bf16x8*)&Bs[(wn * 64 + n * 16 + l15) * 32 + lg * 8];
#pragma unroll
    for (int m = 0; m < 4; ++m)
#pragma unroll
      for (int n = 0; n < 4; ++n)
        acc[m][n] = MFMA(a[m], b[n], acc[m][n]);
    __syncthreads();
  }

#pragma unroll
  for (int m = 0; m < 4; ++m) {
    const int row = brow + wm * 64 + m * 16 + lg * 4;
#pragma unroll
    for (int n = 0; n < 4; ++n) {
      const int col = bcol + wn * 64 + n * 16 + l15;
#pragma unroll
      for (int r = 0; r < 4; ++r) {
        const float v = acc[m][n][r];
        if (F32OUT)
          ((float*)Cout)[(size_t)(row + r) * N + col] = v;
        else
          ((u16*)Cout)[(size_t)(row + r) * N + col] = f2b(v);
      }
    }
  }
}

// ---------------- GEMM1: qkv = x @ w_attn, 4096x3072x1024 ----------------
// 256x192 tile -> grid 16x16 = 256 blocks = exactly 1/CU (100% coverage).
// 512 thr / 8 waves (2M x 4N): per wave 128x48 output (8x3 frags).
// BK=64, double-buffered LDS (112KB), 4 phases per K-tile:
//   P0: ds_read B(6)+A(4) | issue 4 A-gll16 (next tile) | 12 MFMA | barrier
//   P1: ds_read A(4)      | issue 3 B-gll16             | 12 MFMA | barrier
//   P2/P3: ds_read A(4) | 12 MFMA | barrier   (P3: vmcnt(0) drain first)
// Staging issued in P0/P1 -> ~2-3 phase (~900cy) lead before the boundary
// drain, so the wait is ~free. T2 swizzle both sides; T5 setprio; XCD-
// chunked block map (2 A-panels per XCD -> L2 resident).
__global__ __launch_bounds__(512, 1) void k_gemm1(const u16* __restrict__ A,
                                                  const u16* __restrict__ Bt,
                                                  u16* __restrict__ C) {
  __shared__ u16 As[2][256 * 64];  // 32KB each, rows 128B, sw-swizzled
  __shared__ u16 Bs[2][192 * 64];  // 24KB each
  const int tid = threadIdx.x;
  const int lane = tid & 63;
  const int w = tid >> 6;
  const int wm = w >> 2, wn = w & 3;
  const int l15 = lane & 15, lg = lane >> 4;

  const int bid = blockIdx.x;                 // 0..255
  const int lin = (bid & 7) * 32 + (bid >> 3);  // XCD-chunked
  const int bm = lin >> 4, bn = lin & 15;
  const size_t brow = (size_t)bm * 256, bcol = (size_t)bn * 192;

  // staging: row chunk sr, byte col scb; pre-swizzled global col
  const int sr = tid >> 3;                  // 0..63
  const int scb = (tid & 7) * 16;           // bytes
  const int gcol = (scb ^ sw(sr)) >> 1;     // u16 units
  const u16* Ag[4];
#pragma unroll
  for (int i = 0; i < 4; ++i) Ag[i] = A + (brow + i * 64 + sr) * 1024 + gcol;
  const u16* Bg[3];
#pragma unroll
  for (int i = 0; i < 3; ++i) Bg[i] = Bt + (bcol + i * 64 + sr) * 1024 + gcol;

  f32x4 acc[8][3] = {};

  // prologue: stage tile 0 -> buf 0
#pragma unroll
  for (int i = 0; i < 4; ++i) gll16(Ag[i], (char*)As[0] + i * 8192 + tid * 16);
#pragma unroll
  for (int i = 0; i < 3; ++i) gll16(Bg[i], (char*)Bs[0] + i * 8192 + tid * 16);
  asm volatile("s_waitcnt vmcnt(0) lgkmcnt(0)" ::: "memory");
  __builtin_amdgcn_s_barrier();
  __builtin_amdgcn_sched_barrier(0);

  for (int kt = 0; kt < 16; ++kt) {
    const int cur = kt & 1;
    const char* as = (const char*)As[cur];
    const char* bs = (const char*)Bs[cur];
    char* asn = (char*)As[cur ^ 1];
    char* bsn = (char*)Bs[cur ^ 1];
    const bool more = (kt + 1 < 16);
    const int ko = (kt + 1) * 64;  // u16 K offset for next tile staging

    // ---- P0: B frags (held all tile) + A m0/m1; stage next A; MFMA ----
    bf16x8 bfr[3][2];
#pragma unroll
    for (int n = 0; n < 3; ++n) {
      const int row = wn * 48 + n * 16 + l15;
#pragma unroll
      for (int kh = 0; kh < 2; ++kh)
        bfr[n][kh] = *(const bf16x8*)(bs + row * 128 +
                                      ((kh * 64 + lg * 16) ^ sw(row)));
    }
#define GPHASE(MB, STAGE_A, STAGE_B, LAST)                                    \
    {                                                                         \
      bf16x8 af[2][2];                                                        \
      _Pragma("unroll")                                                       \
      for (int mm = 0; mm < 2; ++mm) {                                        \
        const int row = wm * 128 + (MB + mm) * 16 + l15;                      \
        _Pragma("unroll")                                                     \
        for (int kh = 0; kh < 2; ++kh)                                        \
          af[mm][kh] = *(const bf16x8*)(as + row * 128 +                      \
                                        ((kh * 64 + lg * 16) ^ sw(row)));     \
      }                                                                       \
      if (STAGE_A && more) {                                                  \
        _Pragma("unroll")                                                     \
        for (int i = 0; i < 4; ++i)                                           \
          gll16(Ag[i] + ko, asn + i * 8192 + tid * 16);                       \
      }                                                                       \
      if (STAGE_B && more) {                                                  \
        _Pragma("unroll")                                                     \
        for (int i = 0; i < 3; ++i)                                           \
          gll16(Bg[i] + ko, bsn + i * 8192 + tid * 16);                       \
      }                                                                       \
      __builtin_amdgcn_s_setprio(1);                                          \
      _Pragma("unroll")                                                       \
      for (int mm = 0; mm < 2; ++mm)                                          \
        _Pragma("unroll")                                                     \
        for (int n = 0; n < 3; ++n) {                                         \
          acc[MB + mm][n] = MFMA(af[mm][0], bfr[n][0], acc[MB + mm][n]);      \
          acc[MB + mm][n] = MFMA(af[mm][1], bfr[n][1], acc[MB + mm][n]);      \
        }                                                                     \
      __builtin_amdgcn_s_setprio(0);                                          \
      if (LAST) {                                                             \
        asm volatile("s_waitcnt vmcnt(0) lgkmcnt(0)" ::: "memory");           \
      }                                                                       \
      __builtin_amdgcn_s_barrier();                                           \
    }
    GPHASE(0, 1, 0, 0)
    GPHASE(2, 0, 1, 0)
    GPHASE(4, 0, 0, 0)
    GPHASE(6, 0, 0, 1)
#undef GPHASE
    __builtin_amdgcn_sched_barrier(0);
  }

  // ---- epilogue: C write (bf16) ----
#pragma unroll
  for (int m = 0; m < 8; ++m) {
    const size_t row = brow + wm * 128 + m * 16 + lg * 4;
#pragma unroll
    for (int n = 0; n < 3; ++n) {
      const size_t col = bcol + wn * 48 + n * 16 + l15;
#pragma unroll
      for (int r = 0; r < 4; ++r)
        C[(row + r) * 3072 + col] = f2b(acc[m][n][r]);
    }
  }
}

// ---------------- fused causal flash attention (v9) ----------------------
// 256 blocks x 512 thr (8 waves = 4 q-subs x 2 t-subs). 128-q tiles paired
// (k,15-k) -> 34 uniform 64-kv steps. 32x32x16 MFMA; swapped QK^T; P stays
// in register (cvt_pk + shfl_xor(32) exchange). Max-free softmax. K staged
// 2-ahead (tri-buffer gll), V reg-staged 1-ahead, counted vmcnt(1).
__global__ __launch_bounds__(512, 1) void k_attn(const u16* __restrict__ qkv,
                                                 u16* __restrict__ y) {
  __shared__ u16 Kl[3][64 * 64];     // [t][d] sw(t)      24KB
  __shared__ u16 Vt[2][64 * 64];     // [d][t] sw(d)      16KB
  __shared__ float Om[4][64][33];    // O merge (padded)  33.8KB
  __shared__ float Lm[4][2][32];     // l partials        1KB
  const int tid = threadIdx.x;
  const int lane = tid & 63;
  const int w = tid >> 6;
  const int qsub = w & 3, tsub = w >> 2;
  const int l31 = lane & 31, hi = lane >> 5;

  const int lin = blockIdx.x;          // 0..255
  const int xcd = lin & 7;
  const int idx = lin >> 3;            // 0..31
  const int bh = xcd * 4 + (idx >> 3); // 0..31
  const int pidx = idx & 7;            // pair index 0..7
  const int b = bh >> 4, h = bh & 15;

  const u16* Qg = qkv + (size_t)(b * 2048) * 3072 + h * 64;
  const u16* Kg = Qg + 1024;
  const u16* Vg = Qg + 2048;

  const int srow = tid >> 3;
  const int scol = (((tid & 7) * 16) ^ sw(srow)) >> 1;
  const bool vstage = (tid < 256);
  const int t2 = (tid & 255) >> 3;
  const int d8 = (tid & 7) * 8;

  bf16x8 vone;
#pragma unroll
  for (int j = 0; j < 8; ++j) vone[j] = (short)0x3F80;

  const int trow = tsub * 32 + l31;
  int koff[4];
#pragma unroll
  for (int ks = 0; ks < 4; ++ks)
    koff[ks] = trow * 128 + (((ks * 16 + hi * 8) * 2) ^ sw(trow));
  int voff[2][2];
#pragma unroll
  for (int db = 0; db < 2; ++db) {
    const int dl = db * 32 + l31;
#pragma unroll
    for (int ks = 0; ks < 2; ++ks)
      voff[db][ks] = dl * 128 + (((tsub * 32 + ks * 16 + hi * 8) * 2) ^ sw(dl));
  }

  for (int pass = 0; pass < 2; ++pass) {
    const int qi = pass ? (15 - pidx) : pidx;
    const int nt = 2 * (qi + 1);
    const int qb = qi * 128;
    const int qrow = qb + qsub * 32 + l31;

    bf16x8 aq[4];
#pragma unroll
    for (int ks = 0; ks < 4; ++ks) {
      bf16x8 v = *(const bf16x8*)&Qg[(size_t)qrow * 3072 + ks * 16 + hi * 8];
#pragma unroll
      for (int j = 0; j < 8; ++j)
        v[j] = (short)f2b(b2f((u16)v[j]) * 0.18033688011112042f);
      aq[ks] = v;
    }

    f32x16 acc0 = {}, acc1 = {}, accl = {};

    bf16x8 va0, va1;
    {
      bf16x8 v00, v01;
      if (vstage) {
        v00 = *(const bf16x8*)&Vg[(size_t)(2 * t2) * 3072 + d8];
        v01 = *(const bf16x8*)&Vg[(size_t)(2 * t2 + 1) * 3072 + d8];
        va0 = *(const bf16x8*)&Vg[(size_t)(64 + 2 * t2) * 3072 + d8];
        va1 = *(const bf16x8*)&Vg[(size_t)(64 + 2 * t2 + 1) * 3072 + d8];
      }
      gll16(Kg + (size_t)srow * 3072 + scol, (u16*)Kl[0] + tid * 8);
      gll16(Kg + (size_t)(64 + srow) * 3072 + scol, (u16*)Kl[1] + tid * 8);
      if (vstage) {
#pragma unroll
        for (int j = 0; j < 8; ++j) {
          const int d = d8 + j;
          const u32 val = (u32)(u16)v00[j] | ((u32)(u16)v01[j] << 16);
          *(u32*)((char*)Vt[0] + ((d * 128 + t2 * 4) ^ sw(d))) = val;
        }
      }
    }
    asm volatile("s_waitcnt vmcnt(1) lgkmcnt(0)" ::: "memory");
    __builtin_amdgcn_s_barrier();
    __builtin_amdgcn_sched_barrier(0);

    const char* kR = (const char*)Kl[0];
    const char* kN = (const char*)Kl[1];
    char* kN2 = (char*)Kl[2];
    const char* vR = (const char*)Vt[0];
    char* vW = (char*)Vt[1];

    for (int t = 0; t < nt; ++t) {
      const int tf = (t + 2 < 31 ? t + 2 : 31);
      bf16x8 vf0, vf1;
      if (vstage) {
        vf0 = *(const bf16x8*)&Vg[(size_t)(tf * 64 + 2 * t2) * 3072 + d8];
        vf1 = *(const bf16x8*)&Vg[(size_t)(tf * 64 + 2 * t2 + 1) * 3072 + d8];
      }
      gll16(Kg + (size_t)(tf * 64 + srow) * 3072 + scol, (u16*)kN2 + tid * 8);

      f32x16 s = {};
#pragma unroll
      for (int ks = 0; ks < 4; ++ks) {
        const bf16x8 kf = *(const bf16x8*)(kR + koff[ks]);
        s = MFMA32(kf, aq[ks], s);
      }

      float p[16];
      if (t >= nt - 2) {
#pragma unroll
        for (int r = 0; r < 16; ++r) {
          const int kkg = t * 64 + tsub * 32 + (r & 3) + 8 * (r >> 2) + 4 * hi;
          p[r] = exp2f(kkg > qrow ? -1e30f : s[r]);
        }
      } else {
#pragma unroll
        for (int r = 0; r < 16; ++r) p[r] = exp2f(s[r]);
      }

      const u32 X0 = cvtpk(p[0], p[1]),   X1 = cvtpk(p[2], p[3]);
      const u32 X2 = cvtpk(p[4], p[5]),   X3 = cvtpk(p[6], p[7]);
      const u32 X4 = cvtpk(p[8], p[9]),   X5 = cvtpk(p[10], p[11]);
      const u32 X6 = cvtpk(p[12], p[13]), X7 = cvtpk(p[14], p[15]);
      const u32 sx0 = (u32)__shfl_xor((int)X0, 32);
      const u32 sx1 = (u32)__shfl_xor((int)X1, 32);
      const u32 sx2 = (u32)__shfl_xor((int)X2, 32);
      const u32 sx3 = (u32)__shfl_xor((int)X3, 32);
      const u32 sx4 = (u32)__shfl_xor((int)X4, 32);
      const u32 sx5 = (u32)__shfl_xor((int)X5, 32);
      const u32 sx6 = (u32)__shfl_xor((int)X6, 32);
      const u32 sx7 = (u32)__shfl_xor((int)X7, 32);
      union { u32x4 u; bf16x8 h; } c0, c1;
      c0.u[0] = hi ? sx2 : X0;
      c0.u[1] = hi ? sx3 : X1;
      c0.u[2] = hi ? X2 : sx0;
      c0.u[3] = hi ? X3 : sx1;
      c1.u[0] = hi ? sx6 : X4;
      c1.u[1] = hi ? sx7 : X5;
      c1.u[2] = hi ? X6 : sx4;
      c1.u[3] = hi ? X7 : sx5;
      const bf16x8 pb0 = c0.h, pb1 = c1.h;

      accl = MFMA32(vone, pb0, accl);
      accl = MFMA32(vone, pb1, accl);
      const bf16x8 vb00 = *(const bf16x8*)(vR + voff[0][0]);
      const bf16x8 vb01 = *(const bf16x8*)(vR + voff[0][1]);
      const bf16x8 vb10 = *(const bf16x8*)(vR + voff[1][0]);
      const bf16x8 vb11 = *(const bf16x8*)(vR + voff[1][1]);
      acc0 = MFMA32(vb00, pb0, acc0);
      acc0 = MFMA32(vb01, pb1, acc0);
      acc1 = MFMA32(vb10, pb0, acc1);
      acc1 = MFMA32(vb11, pb1, acc1);

      if (vstage && t < nt - 1) {
#pragma unroll
        for (int j = 0; j < 8; ++j) {
          const int d = d8 + j;
          const u32 val = (u32)(u16)va0[j] | ((u32)(u16)va1[j] << 16);
          *(u32*)(vW + ((d * 128 + t2 * 4) ^ sw(d))) = val;
        }
      }
      va0 = vf0; va1 = vf1;
      const char* kt = kR; kR = kN; kN = kN2; kN2 = (char*)kt;
      char* vt_ = (char*)vR; vR = vW; vW = vt_;

      asm volatile("s_waitcnt vmcnt(1) lgkmcnt(0)" ::: "memory");
      __builtin_amdgcn_s_barrier();
      __builtin_amdgcn_sched_barrier(0);
    }

    asm volatile("s_waitcnt vmcnt(0) lgkmcnt(0)" ::: "memory");
    __builtin_amdgcn_s_barrier();
    __builtin_amdgcn_sched_barrier(0);

    if (tsub == 1) {
#pragma unroll
      for (int r = 0; r < 16; ++r) {
        const int d = (r & 3) + 8 * (r >> 2) + 4 * hi;
        Om[qsub][d][l31] = acc0[r];
        Om[qsub][32 + d][l31] = acc1[r];
      }
      Lm[qsub][1][l31] = accl[0];
    } else {
      Lm[qsub][0][l31] = accl[0];
    }
    __syncthreads();
    if (tsub == 0) {
      const float linv = 1.0f / (Lm[qsub][0][l31] + Lm[qsub][1][l31]);
#pragma unroll
      for (int r = 0; r < 16; ++r) {
        const int d = (r & 3) + 8 * (r >> 2) + 4 * hi;
        Om[qsub][d][l31] = (acc0[r] + Om[qsub][d][l31]) * linv;
        Om[qsub][32 + d][l31] = (acc1[r] + Om[qsub][32 + d][l31]) * linv;
      }
    }
    __syncthreads();
    {
      const int qloc = tid >> 2;
      const int dgr = (tid & 3) * 16;
      const size_t yo = (size_t)(b * 2048 + qb + qloc) * 1024 + h * 64 + dgr;
      u32 o[8];
#pragma unroll
      for (int jj = 0; jj < 8; ++jj)
        o[jj] = cvtpk(Om[qloc >> 5][dgr + 2 * jj][qloc & 31],
                      Om[qloc >> 5][dgr + 2 * jj + 1][qloc & 31]);
      u32x4 s0 = {o[0], o[1], o[2], o[3]};
      u32x4 s1 = {o[4], o[5], o[6], o[7]};
      *(u32x4*)&y[yo] = s0;
      *(u32x4*)&y[yo + 8] = s1;
    }
    __syncthreads();
  }
}

// ---------------- host launch ----------------
extern "C" void kernel_launch(void* const* d_in, const int* in_sizes, int n_in,
                              void* d_out, int out_size, void* d_ws, size_t ws_size,
                              hipStream_t stream) {
  const float* x  = (const float*)d_in[0];   // [2,2048,1024]
  const float* wa = (const float*)d_in[1];   // [1024,3072]
  const float* wp = (const float*)d_in[2];   // [1024,1024]
  float* out = (float*)d_out;                // [2,2048,1024] fp32

  u16* xb  = (u16*)d_ws;                 // [4096][1024] bf16
  u16* wat = xb + (size_t)4096 * 1024;   // [3072][1024] bf16 (w_attn^T)
  u16* wpt = wat + (size_t)3072 * 1024;  // [1024][1024] bf16 (w_proj^T)
  u16* qkv = wpt + (size_t)1024 * 1024;  // [4096][3072] bf16
  u16* yb  = qkv + (size_t)4096 * 3072;  // [4096][1024] bf16

  k_cvt<<<4096, 256, 0, stream>>>(x, xb, 4096 * 1024 / 4);
  k_trcvt<<<dim3(3072 / 64, 1024 / 64), 256, 0, stream>>>(wa, wat, 1024, 3072);
  k_trcvt<<<dim3(1024 / 64, 1024 / 64), 256, 0, stream>>>(wp, wpt, 1024, 1024);

  // qkv = x @ w_attn   (bf16 out) -- 256x192 tile, phase-interleaved
  k_gemm1<<<256, 512, 0, stream>>>(xb, wat, qkv);

  // fused causal attention -> y [4096][1024] bf16
  k_attn<<<256, 512, 0, stream>>>(qkv, yb);

  // out = y @ w_proj   (fp32 out)
  k_gemm<1><<<dim3(1024 / 128, 4096 / 128), 256, 0, stream>>>(yb, wpt, out, 4096, 1024, 1024);
}